// Round 1
// baseline (1209.072 us; speedup 1.0000x reference)
//
#include <hip/hip_runtime.h>
#include <math.h>

#define B_ 8
#define T_ 2048
#define D_ 1024
#define H_ 128

static constexpr float SCALE = 0.08838834764831845f; // 1/sqrt(128)

// ---------------------------------------------------------------------------
// Kernel 1: QKV projection. out[b,t,h] = sum_d x[b,t,d] * W[d,h]
// grid (256, 3) blocks of 256 threads; each block computes 64 rows x 128 cols
// for one of {q,k,v}. Plain fp32 LDS-tiled GEMM (BK=16).
// ---------------------------------------------------------------------------
__global__ __launch_bounds__(256) void proj_kernel(
    const float* __restrict__ x,
    const float* __restrict__ Wq,
    const float* __restrict__ Wk,
    const float* __restrict__ Wv,
    float* __restrict__ qkv) {
  constexpr int BK = 16;
  // As transposed [k][row], padded to 65 so stores & reads are conflict-free.
  __shared__ float As[BK][65];
  __shared__ float Bs[BK][H_];

  const int sel = blockIdx.y;
  const float* W = (sel == 0) ? Wq : (sel == 1 ? Wk : Wv);
  float* out = qkv + (size_t)sel * (size_t)(B_ * T_ * H_);

  const int row0 = blockIdx.x * 64;
  const int tid = threadIdx.x;
  const int tx = tid & 15;   // col group: 8 cols each -> 128
  const int ty = tid >> 4;   // row group: 4 rows each -> 64

  float c[4][8];
#pragma unroll
  for (int i = 0; i < 4; ++i)
#pragma unroll
    for (int j = 0; j < 8; ++j) c[i][j] = 0.f;

  for (int k0 = 0; k0 < D_; k0 += BK) {
    // stage x tile (64 rows x 16 k) transposed into As
    {
      int row = tid >> 2;            // 0..63
      int coff = (tid & 3) * 4;      // 0,4,8,12
      float4 xv = *(const float4*)(x + (size_t)(row0 + row) * D_ + k0 + coff);
      As[coff + 0][row] = xv.x;
      As[coff + 1][row] = xv.y;
      As[coff + 2][row] = xv.z;
      As[coff + 3][row] = xv.w;
    }
    // stage W tile (16 k x 128 cols)
#pragma unroll
    for (int w = 0; w < 2; ++w) {
      int fid = tid + w * 256;       // 0..511 float4 slots
      int kr = fid >> 5;             // 0..15
      int coff = (fid & 31) * 4;     // 0..124
      *(float4*)&Bs[kr][coff] = *(const float4*)(W + (size_t)(k0 + kr) * H_ + coff);
    }
    __syncthreads();

#pragma unroll
    for (int k = 0; k < BK; ++k) {
      float a[4], bb[8];
#pragma unroll
      for (int i = 0; i < 4; ++i) a[i] = As[k][ty * 4 + i];
#pragma unroll
      for (int j = 0; j < 8; ++j) bb[j] = Bs[k][tx * 8 + j];
#pragma unroll
      for (int i = 0; i < 4; ++i)
#pragma unroll
        for (int j = 0; j < 8; ++j) c[i][j] += a[i] * bb[j];
    }
    __syncthreads();
  }

#pragma unroll
  for (int i = 0; i < 4; ++i) {
    size_t o = (size_t)(row0 + ty * 4 + i) * H_ + tx * 8;
    *(float4*)(out + o)     = make_float4(c[i][0], c[i][1], c[i][2], c[i][3]);
    *(float4*)(out + o + 4) = make_float4(c[i][4], c[i][5], c[i][6], c[i][7]);
  }
}

// ---------------------------------------------------------------------------
// Kernel 2: causal flash attention over precomputed q,k,v (all fp32, [B*T, H]).
// grid 1024 blocks (8 batches x 128 query tiles of 16), 256 threads.
// Online softmax; K/V chunks of 32 staged in LDS (+4 pad breaks the 32-way
// bank aliasing of 512B rows). Heavy tiles (large q0) launched first.
// ---------------------------------------------------------------------------
__global__ __launch_bounds__(256) void attn_kernel(
    const float* __restrict__ qkv, float* __restrict__ out) {
  constexpr int TQ = 16, TK = 32;
  __shared__ alignas(16) float Qs[TQ][H_];
  __shared__ alignas(16) float Ks[TK][H_ + 4];
  __shared__ alignas(16) float Vs[TK][H_ + 4];
  __shared__ float Sb[TQ][TK + 1];
  __shared__ float mM[TQ], lL[TQ], aA[TQ];

  const float* qp = qkv;
  const float* kp = qkv + (size_t)(B_ * T_ * H_);
  const float* vp = qkv + (size_t)2 * (B_ * T_ * H_);

  const int b = blockIdx.x >> 7;
  const int q0 = (127 - (blockIdx.x & 127)) * TQ;  // heavy tiles first
  const int tid = threadIdx.x;

  // load Q tile (16 x 128)
#pragma unroll
  for (int w = 0; w < 2; ++w) {
    int i = tid + w * 256;           // 0..511 float4 slots
    int qr = i >> 5;                 // 0..15
    int cc = (i & 31) * 4;           // 0..124
    *(float4*)&Qs[qr][cc] =
        *(const float4*)(qp + ((size_t)(b * T_ + q0 + qr)) * H_ + cc);
  }
  if (tid < TQ) { mM[tid] = -INFINITY; lL[tid] = 0.f; }

  float O[8];
#pragma unroll
  for (int j = 0; j < 8; ++j) O[j] = 0.f;

  const int r = tid >> 4;            // query row 0..15
  const int cbase = (tid & 15) * 8;  // 8 head-dims per thread

  const int nch = q0 / TK + 1;       // key chunks needed (covers diag)
  for (int ch = 0; ch < nch; ++ch) {
    const int s0 = ch * TK;
    __syncthreads();  // previous PV done before overwriting Ks/Vs
    // stage K/V chunk (32 x 128 each)
#pragma unroll
    for (int w = 0; w < 4; ++w) {
      int i = tid + w * 256;         // 0..1023 float4 slots
      int rr = i >> 5;               // 0..31
      int cc = (i & 31) * 4;
      size_t g = ((size_t)(b * T_ + s0 + rr)) * H_ + cc;
      *(float4*)&Ks[rr][cc] = *(const float4*)(kp + g);
      *(float4*)&Vs[rr][cc] = *(const float4*)(vp + g);
    }
    __syncthreads();

    // scores: 16x32 dots, 2 per thread
#pragma unroll
    for (int t2 = 0; t2 < 2; ++t2) {
      int idx = tid + t2 * 256;
      int rr = idx >> 5;             // 0..15
      int ss = idx & 31;             // 0..31
      float acc = 0.f;
#pragma unroll
      for (int cc = 0; cc < H_; cc += 4) {
        float4 qv = *(const float4*)&Qs[rr][cc];
        float4 kv = *(const float4*)&Ks[ss][cc];
        acc += qv.x * kv.x + qv.y * kv.y + qv.z * kv.z + qv.w * kv.w;
      }
      int sg = s0 + ss;
      Sb[rr][ss] = (sg <= q0 + rr) ? acc * SCALE : -INFINITY;
    }
    __syncthreads();

    // online softmax state update (one thread per query row)
    if (tid < TQ) {
      float mo = mM[tid];
      float mc = -INFINITY;
#pragma unroll
      for (int s = 0; s < TK; ++s) mc = fmaxf(mc, Sb[tid][s]);
      float mn = fmaxf(mo, mc);
      float alpha = __expf(mo - mn);   // mo=-inf on first chunk -> 0
      float l = lL[tid] * alpha;
#pragma unroll
      for (int s = 0; s < TK; ++s) {
        float p = __expf(Sb[tid][s] - mn);  // masked -inf -> 0
        Sb[tid][s] = p;
        l += p;
      }
      mM[tid] = mn; lL[tid] = l; aA[tid] = alpha;
    }
    __syncthreads();

    // O = O*alpha + P @ V
    {
      float alpha = aA[r];
#pragma unroll
      for (int j = 0; j < 8; ++j) O[j] *= alpha;
#pragma unroll 8
      for (int s = 0; s < TK; ++s) {
        float p = Sb[r][s];
        float4 v0 = *(const float4*)&Vs[s][cbase];
        float4 v1 = *(const float4*)&Vs[s][cbase + 4];
        O[0] += p * v0.x; O[1] += p * v0.y; O[2] += p * v0.z; O[3] += p * v0.w;
        O[4] += p * v1.x; O[5] += p * v1.y; O[6] += p * v1.z; O[7] += p * v1.w;
      }
    }
  }

  const float linv = 1.0f / lL[r];
  size_t o = ((size_t)(b * T_ + q0 + r)) * H_ + cbase;
  *(float4*)(out + o)     = make_float4(O[0] * linv, O[1] * linv, O[2] * linv, O[3] * linv);
  *(float4*)(out + o + 4) = make_float4(O[4] * linv, O[5] * linv, O[6] * linv, O[7] * linv);
}

// ---------------------------------------------------------------------------
extern "C" void kernel_launch(void* const* d_in, const int* in_sizes, int n_in,
                              void* d_out, int out_size, void* d_ws, size_t ws_size,
                              hipStream_t stream) {
  const float* x  = (const float*)d_in[0];
  const float* Wq = (const float*)d_in[1];
  const float* Wk = (const float*)d_in[2];
  const float* Wv = (const float*)d_in[3];
  float* out = (float*)d_out;
  float* qkv = (float*)d_ws;  // 3 * B*T*H fp32 = 25.2 MB

  proj_kernel<<<dim3((B_ * T_) / 64, 3), 256, 0, stream>>>(x, Wq, Wk, Wv, qkv);
  attn_kernel<<<dim3(B_ * (T_ / 16)), 256, 0, stream>>>(qkv, out);
}

// Round 2
// 206.674 us; speedup vs baseline: 5.8502x; 5.8502x over previous
//
#include <hip/hip_runtime.h>
#include <math.h>

#define B_ 8
#define T_ 2048
#define D_ 1024
#define H_ 128
#define BT (B_ * T_)

typedef short bf16x8 __attribute__((ext_vector_type(8)));
typedef float f32x4 __attribute__((ext_vector_type(4)));

static constexpr float SCALE = 0.08838834764831845f;  // 1/sqrt(128)

__device__ inline unsigned short f2b(float f) {
  unsigned int u = __float_as_uint(f);
  u += 0x7FFF + ((u >> 16) & 1);  // RNE
  return (unsigned short)(u >> 16);
}
__device__ inline unsigned int pk2(float a, float b) {
  return (unsigned int)f2b(a) | ((unsigned int)f2b(b) << 16);
}

// ---------------------------------------------------------------------------
// Setup: W[d][h] fp32 -> Wt[sel][h][d] bf16 (transposed so proj B-frags are
// contiguous LDS reads). 0.75 MB total, one-shot.
// ---------------------------------------------------------------------------
__global__ __launch_bounds__(256) void wcvt_kernel(
    const float* __restrict__ Wq, const float* __restrict__ Wk,
    const float* __restrict__ Wv, short* __restrict__ Wt) {
  const int sel = blockIdx.y;
  const float* W = sel == 0 ? Wq : (sel == 1 ? Wk : Wv);
  short* dst = Wt + (size_t)sel * D_ * H_;
  int slot = blockIdx.x * 256 + threadIdx.x;  // 32768 slots
  int d = slot >> 5, hg = slot & 31;
  float4 w = *(const float4*)(W + (size_t)d * H_ + hg * 4);
  dst[(size_t)(hg * 4 + 0) * D_ + d] = (short)f2b(w.x);
  dst[(size_t)(hg * 4 + 1) * D_ + d] = (short)f2b(w.y);
  dst[(size_t)(hg * 4 + 2) * D_ + d] = (short)f2b(w.z);
  dst[(size_t)(hg * 4 + 3) * D_ + d] = (short)f2b(w.w);
}

// ---------------------------------------------------------------------------
// Proj: C = X * W via bf16 MFMA. Block = 256 thr (4 waves), 64 rows x 128 cols.
// sel 0->q (bf16 row-major), 1->k, 2->v written TRANSPOSED as vt[b][h][t].
// ---------------------------------------------------------------------------
__global__ __launch_bounds__(256) void proj_kernel(
    const float* __restrict__ x, const short* __restrict__ Wt,
    short* __restrict__ qb, short* __restrict__ kb, short* __restrict__ vtb) {
  __shared__ alignas(16) char smem[27648];
  short* Xs = (short*)smem;           // [64][72] bf16
  short* Ws = (short*)(smem + 9216);  // [128][72] bf16

  const int tid = threadIdx.x;
  const int wave = tid >> 6, lane = tid & 63;
  const int ln = lane & 15, quad = lane >> 4;
  const int sel = blockIdx.y;
  const int row0 = blockIdx.x * 64;
  const short* W = Wt + (size_t)sel * D_ * H_;

  f32x4 acc[8];
#pragma unroll
  for (int i = 0; i < 8; ++i) acc[i] = (f32x4){0.f, 0.f, 0.f, 0.f};

  for (int k0 = 0; k0 < D_; k0 += 64) {
    if (k0) __syncthreads();
    // stage X tile 64x64 (fp32 -> bf16)
#pragma unroll
    for (int i = 0; i < 4; ++i) {
      int slot = tid + i * 256;
      int r = slot >> 4, g = slot & 15;
      float4 xv = *(const float4*)(x + (size_t)(row0 + r) * D_ + k0 + g * 4);
      unsigned int* p = (unsigned int*)&Xs[r * 72 + g * 4];
      p[0] = pk2(xv.x, xv.y);
      p[1] = pk2(xv.z, xv.w);
    }
    // stage Wt tile 128x64 (already bf16, contiguous)
#pragma unroll
    for (int i = 0; i < 4; ++i) {
      int slot = tid + i * 256;
      int n = slot >> 3, g = slot & 7;
      *(int4*)&Ws[n * 72 + g * 8] = *(const int4*)(W + (size_t)n * D_ + k0 + g * 8);
    }
    __syncthreads();
#pragma unroll
    for (int kk = 0; kk < 2; ++kk) {
      bf16x8 a = *(bf16x8*)&Xs[(wave * 16 + ln) * 72 + kk * 32 + quad * 8];
#pragma unroll
      for (int nt = 0; nt < 8; ++nt) {
        bf16x8 bb = *(bf16x8*)&Ws[(nt * 16 + ln) * 72 + kk * 32 + quad * 8];
        acc[nt] = __builtin_amdgcn_mfma_f32_16x16x32_bf16(a, bb, acc[nt], 0, 0, 0);
      }
    }
  }

  if (sel < 2) {
    short* out = sel ? kb : qb;
#pragma unroll
    for (int nt = 0; nt < 8; ++nt)
#pragma unroll
      for (int r = 0; r < 4; ++r) {
        int row = row0 + wave * 16 + quad * 4 + r;
        out[(size_t)row * H_ + nt * 16 + ln] = (short)f2b(acc[nt][r]);
      }
  } else {
    // transpose through LDS, write vt[b][h][t] coalesced
    __syncthreads();
    short* Cs = (short*)smem;  // [128][72] bf16, aliases Xs/Ws
#pragma unroll
    for (int nt = 0; nt < 8; ++nt)
#pragma unroll
      for (int r = 0; r < 4; ++r)
        Cs[(nt * 16 + ln) * 72 + wave * 16 + quad * 4 + r] = (short)f2b(acc[nt][r]);
    __syncthreads();
    const int b = row0 >> 11, t0 = row0 & 2047;
#pragma unroll
    for (int i = 0; i < 4; ++i) {
      int slot = tid + i * 256;
      int h = slot >> 3, g = slot & 7;
      *(int4*)(vtb + (size_t)(b * H_ + h) * T_ + t0 + g * 8) = *(int4*)&Cs[h * 72 + g * 8];
    }
  }
}

// ---------------------------------------------------------------------------
// Attention: flash-style, MFMA. Block = 256 thr (4 waves) = 32 queries.
// Chunks of 64 keys. Q frags in registers; K and V^T staged in LDS.
// Waves split keys (16 each) for QK^T, split head-dims (32 each) for PV.
// ---------------------------------------------------------------------------
__global__ __launch_bounds__(256) void attn_kernel(
    const short* __restrict__ qb, const short* __restrict__ kb,
    const short* __restrict__ vtb, float* __restrict__ out) {
  __shared__ alignas(16) short Ks[64 * 136];   // [64][136] bf16 (pad +8)
  __shared__ alignas(16) short Vt[128 * 72];   // [128][72] bf16 (pad +8)
  __shared__ alignas(16) float Sf[32 * 65];    // [32][65] f32 (pad +1)
  __shared__ alignas(16) short P[32 * 72];     // [32][72] bf16 (pad +8)
  __shared__ float aA[32], lL[32];

  const int tid = threadIdx.x;
  const int wave = tid >> 6, lane = tid & 63;
  const int ln = lane & 15, quad = lane >> 4;
  const int b = blockIdx.x >> 6;
  const int tile = 63 - (blockIdx.x & 63);  // heavy tiles first
  const int q0 = tile * 32;

  // Q fragments: 2 M-tiles x 4 K-steps, loaded once, live in registers
  bf16x8 qfr[2][4];
#pragma unroll
  for (int m = 0; m < 2; ++m)
#pragma unroll
    for (int kk = 0; kk < 4; ++kk)
      qfr[m][kk] = *(const bf16x8*)(qb + (size_t)(b * T_ + q0 + m * 16 + ln) * H_ +
                                    kk * 32 + quad * 8);

  f32x4 oacc[2][2];
#pragma unroll
  for (int m = 0; m < 2; ++m)
#pragma unroll
    for (int nt = 0; nt < 2; ++nt) oacc[m][nt] = (f32x4){0.f, 0.f, 0.f, 0.f};

  // softmax state: 8 lanes per query row, state replicated in registers
  const int srow = tid >> 3, l8 = tid & 7;
  float m_run = -INFINITY, l_run = 0.f;

  const int nch = ((q0 + 31) >> 6) + 1;
  for (int ch = 0; ch < nch; ++ch) {
    const int s0 = ch * 64;
    if (ch) __syncthreads();  // prev PV done before restaging
    // stage K chunk 64x128
#pragma unroll
    for (int i = 0; i < 4; ++i) {
      int slot = tid + i * 256;
      int r = slot >> 4, g = slot & 15;
      *(int4*)&Ks[r * 136 + g * 8] =
          *(const int4*)(kb + (size_t)(b * T_ + s0 + r) * H_ + g * 8);
    }
    // stage V^T chunk 128x64
#pragma unroll
    for (int i = 0; i < 4; ++i) {
      int slot = tid + i * 256;
      int h = slot >> 3, g = slot & 7;
      *(int4*)&Vt[h * 72 + g * 8] =
          *(const int4*)(vtb + (size_t)(b * H_ + h) * T_ + s0 + g * 8);
    }
    __syncthreads();

    // S = Q K^T : each wave does 32 queries x 16 keys (n0 = wave*16)
    f32x4 sacc[2];
    sacc[0] = (f32x4){0.f, 0.f, 0.f, 0.f};
    sacc[1] = (f32x4){0.f, 0.f, 0.f, 0.f};
#pragma unroll
    for (int kk = 0; kk < 4; ++kk) {
      bf16x8 bk = *(bf16x8*)&Ks[(wave * 16 + ln) * 136 + kk * 32 + quad * 8];
#pragma unroll
      for (int m = 0; m < 2; ++m)
        sacc[m] = __builtin_amdgcn_mfma_f32_16x16x32_bf16(qfr[m][kk], bk, sacc[m], 0, 0, 0);
    }
#pragma unroll
    for (int m = 0; m < 2; ++m)
#pragma unroll
      for (int r = 0; r < 4; ++r)
        Sf[(m * 16 + quad * 4 + r) * 65 + wave * 16 + ln] = sacc[m][r];
    __syncthreads();

    // online softmax: 8 lanes per row, 8 cols each
    float sv[8];
    const int qg = q0 + srow;
#pragma unroll
    for (int i = 0; i < 8; ++i) {
      float s = Sf[srow * 65 + l8 * 8 + i] * SCALE;
      sv[i] = (s0 + l8 * 8 + i <= qg) ? s : -INFINITY;
    }
    float mx = sv[0];
#pragma unroll
    for (int i = 1; i < 8; ++i) mx = fmaxf(mx, sv[i]);
    mx = fmaxf(mx, __shfl_xor(mx, 1));
    mx = fmaxf(mx, __shfl_xor(mx, 2));
    mx = fmaxf(mx, __shfl_xor(mx, 4));
    const float mnew = fmaxf(m_run, mx);
    const float alpha = __expf(m_run - mnew);  // first chunk: exp(-inf)=0
    float p[8], ps = 0.f;
#pragma unroll
    for (int i = 0; i < 8; ++i) {
      p[i] = __expf(sv[i] - mnew);  // masked -inf -> 0
      ps += p[i];
    }
    ps += __shfl_xor(ps, 1);
    ps += __shfl_xor(ps, 2);
    ps += __shfl_xor(ps, 4);
    l_run = l_run * alpha + ps;
    m_run = mnew;
    int4 pw;
    pw.x = (int)pk2(p[0], p[1]);
    pw.y = (int)pk2(p[2], p[3]);
    pw.z = (int)pk2(p[4], p[5]);
    pw.w = (int)pk2(p[6], p[7]);
    *(int4*)&P[srow * 72 + l8 * 8] = pw;
    if (l8 == 0) aA[srow] = alpha;
    __syncthreads();

    // O = O*alpha + P V : each wave does 32 queries x 32 head-dims (h0=wave*32)
    const int h0 = wave * 32;
    float ar[2][4];
#pragma unroll
    for (int m = 0; m < 2; ++m)
#pragma unroll
      for (int r = 0; r < 4; ++r) ar[m][r] = aA[m * 16 + quad * 4 + r];
#pragma unroll
    for (int m = 0; m < 2; ++m)
#pragma unroll
      for (int nt = 0; nt < 2; ++nt)
#pragma unroll
        for (int r = 0; r < 4; ++r) oacc[m][nt][r] *= ar[m][r];
#pragma unroll
    for (int ks = 0; ks < 2; ++ks) {
      bf16x8 pa[2];
      pa[0] = *(bf16x8*)&P[ln * 72 + ks * 32 + quad * 8];
      pa[1] = *(bf16x8*)&P[(16 + ln) * 72 + ks * 32 + quad * 8];
#pragma unroll
      for (int nt = 0; nt < 2; ++nt) {
        bf16x8 bv = *(bf16x8*)&Vt[(h0 + nt * 16 + ln) * 72 + ks * 32 + quad * 8];
#pragma unroll
        for (int m = 0; m < 2; ++m)
          oacc[m][nt] = __builtin_amdgcn_mfma_f32_16x16x32_bf16(pa[m], bv, oacc[m][nt], 0, 0, 0);
      }
    }
  }

  // finalize: divide by l, write fp32 output
  if (l8 == 0) lL[srow] = l_run;
  __syncthreads();
  const int h0 = wave * 32;
#pragma unroll
  for (int m = 0; m < 2; ++m) {
    float linv[4];
#pragma unroll
    for (int r = 0; r < 4; ++r) linv[r] = 1.f / lL[m * 16 + quad * 4 + r];
#pragma unroll
    for (int nt = 0; nt < 2; ++nt)
#pragma unroll
      for (int r = 0; r < 4; ++r) {
        int row = q0 + m * 16 + quad * 4 + r;
        out[(size_t)(b * T_ + row) * H_ + h0 + nt * 16 + ln] = oacc[m][nt][r] * linv[r];
      }
  }
}

// ---------------------------------------------------------------------------
extern "C" void kernel_launch(void* const* d_in, const int* in_sizes, int n_in,
                              void* d_out, int out_size, void* d_ws, size_t ws_size,
                              hipStream_t stream) {
  const float* x  = (const float*)d_in[0];
  const float* Wq = (const float*)d_in[1];
  const float* Wk = (const float*)d_in[2];
  const float* Wv = (const float*)d_in[3];
  float* out = (float*)d_out;

  char* ws = (char*)d_ws;
  short* qb  = (short*)(ws);                // 4 MB  q  bf16 [BT][128]
  short* kb  = (short*)(ws + 4194304);      // 4 MB  k  bf16 [BT][128]
  short* vtb = (short*)(ws + 8388608);      // 4 MB  v^T bf16 [B][128][T]
  short* Wt  = (short*)(ws + 12582912);     // 0.75 MB  W^T bf16 [3][128][1024]

  wcvt_kernel<<<dim3(128, 3), 256, 0, stream>>>(Wq, Wk, Wv, Wt);
  proj_kernel<<<dim3(BT / 64, 3), 256, 0, stream>>>(x, Wt, qb, kb, vtb);
  attn_kernel<<<dim3(8 * 64), 256, 0, stream>>>(qb, kb, vtb, out);
}